// Round 16
// baseline (78.109 us; speedup 1.0000x reference)
//
#include <hip/hip_runtime.h>
#include <math.h>

// Problem constants
#define NB 4
#define NC 2048
#define NH 8
#define NK 128
#define NG 255          // a-grid points per (b,h)

// exp2-domain logit scale: log2(e)/sqrt(128)
#define A2SCALE (1.4426950408889634f * 0.08838834764831845f)

typedef __attribute__((ext_vector_type(8))) short bf16x8;
typedef __attribute__((ext_vector_type(4))) float f32x4;

// ---------------- ws layout (float offsets) ----------------
// wspart [4][2048]            @ 0        (8192)
// W2 f32 [8][128][128]        @ 8192     (131072)
// qs     [32][2048]           @ 139264
// ks     [32][2048]           @ 204800
// X_bf   [4b][64ig][8nt][64lane][8j] bf16 @ 270336 (1,048,576 us = 524,288 f)
// mmu    [32][4] uint         @ 794624
// pz f32 [32][8sl][255]       @ 794752   (65,280)
// tablef [32][255][128] f32   @ 860032   (1,044,480)
// pC bf16[32][8sl][255][128]  @ 1904512  (8,355,840 us = 4,177,920 f)
// end 6,082,432 < 8,652,864 (R0-proven footprint)
#define OFF_W2   8192
#define OFF_QS   139264
#define OFF_KS   204800
#define OFF_XB   270336
#define OFF_MMU  794624
#define OFF_PZ   794752
#define OFF_TF   860032
#define OFF_PC   1904512

__device__ static inline float exp2_hw(float x) {
#if __has_builtin(__builtin_amdgcn_exp2f)
    return __builtin_amdgcn_exp2f(x);
#else
    float r;
    asm volatile("v_exp_f32 %0, %1\n\ts_nop 1" : "=v"(r) : "v"(x));
    return r;
#endif
}

__device__ static inline unsigned cvtpk(float lo, float hi) {
    unsigned r;
    asm("v_cvt_pk_bf16_f32 %0, %1, %2" : "=v"(r) : "v"(lo), "v"(hi));
    return r;
}

__device__ static inline unsigned short f2bf(float f) {
    unsigned u = __float_as_uint(f);
    return (unsigned short)((u + 0x7FFFu + ((u >> 16) & 1u)) >> 16);
}

__device__ static inline bf16x8 pack8(float4 a, float4 b) {
    union { unsigned u[4]; bf16x8 v; } r;
    r.u[0] = cvtpk(a.x, a.y);
    r.u[1] = cvtpk(a.z, a.w);
    r.u[2] = cvtpk(b.x, b.y);
    r.u[3] = cvtpk(b.z, b.w);
    return r.v;
}

// order-preserving float <-> uint key (for atomicMin/Max)
__device__ static inline unsigned fenc(float f) {
    unsigned b = __float_as_uint(f);
    return (b & 0x80000000u) ? ~b : (b | 0x80000000u);
}
__device__ static inline float fdec(unsigned k) {
    return __uint_as_float((k & 0x80000000u) ? (k & 0x7FFFFFFFu) : ~k);
}

// 8 exps of (a*k + negM) packed to a bf16x8 A-fragment; accumulates sum in z
__device__ static inline bf16x8 pexp8s(float4 ka, float4 kb, float a, float negM,
                                       float& z) {
    float e0 = exp2_hw(fmaf(a, ka.x, negM));
    float e1 = exp2_hw(fmaf(a, ka.y, negM));
    float e2 = exp2_hw(fmaf(a, ka.z, negM));
    float e3 = exp2_hw(fmaf(a, ka.w, negM));
    float e4 = exp2_hw(fmaf(a, kb.x, negM));
    float e5 = exp2_hw(fmaf(a, kb.y, negM));
    float e6 = exp2_hw(fmaf(a, kb.z, negM));
    float e7 = exp2_hw(fmaf(a, kb.w, negM));
    z += ((e0 + e1) + (e2 + e3)) + ((e4 + e5) + (e6 + e7));
    union { unsigned u[4]; bf16x8 v; } r;
    r.u[0] = cvtpk(e0, e1);
    r.u[1] = cvtpk(e2, e3);
    r.u[2] = cvtpk(e4, e5);
    r.u[3] = cvtpk(e6, e7);
    return r.v;
}

// ---- prep1: (blk<64) wsum + mmu init ; (blk>=64) W2 ----  grid 576 x 256
// (R15-proven verbatim)
__global__ __launch_bounds__(256) void k_prep1(const float* __restrict__ Wq,
                                               const float* __restrict__ Wk,
                                               const float* __restrict__ Wv,
                                               const float* __restrict__ Wo,
                                               float* __restrict__ wspart,
                                               float* __restrict__ W2,
                                               unsigned* __restrict__ mmu) {
    int blk = blockIdx.x;
    int tid = threadIdx.x;
    __shared__ float sh[256];
    if (blk < 64) {
        int which = blk >> 5, h = (blk >> 2) & 7, eq = blk & 3;
        const float* W = which ? Wk : Wq;
        int m = tid & 127, part = tid >> 7;
        const float* base = W + (h * 128 + eq * 32 + part * 16) * 128 + m;
        float s = 0.f;
#pragma unroll
        for (int e = 0; e < 16; ++e) s += base[e * 128];
        if (part) sh[m] = s;
        __syncthreads();
        if (!part) wspart[eq * 2048 + which * 1024 + h * 128 + m] = s + sh[m];
        if (blk == 0 && tid < 128)
            mmu[tid] = (tid & 1) ? 0u : 0xFFFFFFFFu;   // min=MAXKEY, max=0
    } else {
        int idx = blk - 64;                    // 0..511
        int h = idx >> 6;
        int kl = tid >> 7;                     // 0..1
        int kk = (idx & 63) * 2 + kl;
        int m = tid & 127;
        float* wo_s = sh;                      // [2][128]
        wo_s[kl * 128 + m] = Wo[kk * 1024 + h * 128 + m];
        __syncthreads();
        const float* base = Wv + (h * 128) * 128 + m;
        const float* wrow = &wo_s[kl * 128];
        float s = 0.f;
#pragma unroll 4
        for (int e = 0; e < 128; ++e) s += base[e * 128] * wrow[e];
        W2[(h * 128 + kk) * 128 + m] = s;
    }
}

// ---- prep2: qs/ks + X_bf frag emit + mmu atomic min/max ----  grid 256 x 256
// (R15-proven verbatim)
__global__ __launch_bounds__(256) void k_prep2(const float* __restrict__ x,
                                               const float* __restrict__ wspart,
                                               float* __restrict__ qs,
                                               float* __restrict__ ks,
                                               unsigned short* __restrict__ xbf,
                                               unsigned* __restrict__ mmu) {
    __shared__ float xs[32][129];
    __shared__ float wsum[2048];
    int tid = threadIdx.x;
    int blk = blockIdx.x;
    for (int j = tid; j < 2048; j += 256)
        wsum[j] = wspart[j] + wspart[2048 + j] + wspart[4096 + j] + wspart[6144 + j];
    int row0 = blk * 32;
    for (int j = tid; j < 32 * 128; j += 256) {
        int r = j >> 7, m = j & 127;
        xs[r][m] = x[(size_t)(row0 + r) * 128 + m];
    }
    __syncthreads();
#pragma unroll
    for (int jj = 0; jj < 2; ++jj) {
        int o = tid + 256 * jj;
        int r = o & 31;
        int q = o >> 5;
        int which = q >> 3, h = q & 7;
        const float* wrow = &wsum[which * 1024 + h * 128];
        const float* xrow = &xs[r][0];
        float s = 0.f;
#pragma unroll 4
        for (int m = 0; m < 128; ++m) s += xrow[m] * wrow[m];
        int row = row0 + r, b = row >> 11, t = row & 2047;
        float* dst = which ? ks : qs;
        dst[(b * 8 + h) * 2048 + t] = s;
        float gmn = s, gmx = s;
#pragma unroll
        for (int off = 1; off <= 16; off <<= 1) {
            gmn = fminf(gmn, __shfl_xor(gmn, off));
            gmx = fmaxf(gmx, __shfl_xor(gmx, off));
        }
        if (r == 0) {
            unsigned* mb = &mmu[(b * 8 + h) * 4 + which * 2];
            atomicMin(&mb[0], fenc(gmn));
            atomicMax(&mb[1], fenc(gmx));
        }
    }
    // X_bf B-frags for this (b, ig)
    {
        int b = row0 >> 11;
        int ig = (row0 >> 5) & 63;
        unsigned short* xb = xbf + (size_t)(b * 64 + ig) * 4096;
#pragma unroll
        for (int qq = 0; qq < 2; ++qq) {
            int q = tid + qq * 256;            // 0..511
            int nt = q >> 6, lane = q & 63;
            int l4 = lane >> 4, m = nt * 16 + (lane & 15);
            int ib = l4 * 8;
            union { unsigned u[4]; uint4 v; } pk;
            pk.u[0] = cvtpk(xs[ib + 0][m], xs[ib + 1][m]);
            pk.u[1] = cvtpk(xs[ib + 2][m], xs[ib + 3][m]);
            pk.u[2] = cvtpk(xs[ib + 4][m], xs[ib + 5][m]);
            pk.u[3] = cvtpk(xs[ib + 6][m], xs[ib + 7][m]);
            *(uint4*)&xb[(size_t)nt * 512 + lane * 8] = pk.v;
        }
    }
}

// ---- k_c: C partials (bf16) = E @ X, 8 i-slices, 4 blocks/CU ----
// grid 1024 x 256: 32 bh x 4 gt x 8 sl. R14's proven 3-buf counted-vmcnt(2)
// convoy, 8 chunks/block. Prologue = mmu decode + 256-float ks slice.
__global__ __launch_bounds__(256, 4) void k_c(const float* __restrict__ ks,
                                              const unsigned short* __restrict__ xbf,
                                              const unsigned* __restrict__ mmu,
                                              unsigned short* __restrict__ pC,
                                              float* __restrict__ pz) {
    int L = blockIdx.x;
    int xcd = L & 7, s = L >> 3;           // s 0..127
    int bh = xcd * 4 + (s >> 5);
    int rem = s & 31;
    int gt = rem >> 3, sl = rem & 7;
    int b = bh >> 3;
    int tid = threadIdx.x;
    int lane = tid & 63, wid = tid >> 6;
    int l15 = lane & 15, l4 = lane >> 4;

    __shared__ float ks_s[256];
    __shared__ __align__(16) unsigned short u_l[3][4096];

    float amin = fdec(mmu[bh * 4]) * A2SCALE;
    float amax = fdec(mmu[bh * 4 + 1]) * A2SCALE;
    float hstep = fmaxf(amax - amin, 1e-6f) * (1.f / (NG - 1));
    float kmn = fdec(mmu[bh * 4 + 2]);
    float kmx = fdec(mmu[bh * 4 + 3]);

    if (tid < 64)
        ((float4*)ks_s)[tid] = ((const float4*)(ks + bh * 2048 + sl * 256))[tid];

    int grow = gt * 64 + wid * 16 + l15;
    float a = fmaf((float)grow, hstep, amin);
    float negM = -(a > 0.f ? a * kmx : a * kmn);   // global max -> slice-consistent
    float zacc = 0.f;

    f32x4 acc[8];
#pragma unroll
    for (int n = 0; n < 8; ++n) acc[n] = (f32x4)0.f;

    __syncthreads();   // ks_s ready; NO DMAs issued yet (counting invariant)

    const unsigned short* gxb = xbf + (size_t)b * 262144 + (size_t)sl * 32768;

#define DMA(cnv, buf) do {                                                     \
    const unsigned short* src_ = gxb + (size_t)(cnv) * 4096;                   \
    _Pragma("unroll")                                                          \
    for (int q_ = 0; q_ < 2; ++q_) {                                           \
        int seg_ = q_ * 4 + wid;                                               \
        __builtin_amdgcn_global_load_lds(                                      \
            (const __attribute__((address_space(1))) unsigned int*)(src_ + seg_ * 512 + lane * 8), \
            (__attribute__((address_space(3))) unsigned int*)(&u_l[buf][seg_ * 512]),              \
            16, 0, 0);                                                         \
    }                                                                          \
} while (0)

    DMA(0, 0);
    DMA(1, 1);
    for (int cn = 0; cn < 7; ++cn) {
        int cur = cn % 3;
        float4 ka = *(const float4*)&ks_s[cn * 32 + l4 * 8];
        float4 kb = *(const float4*)&ks_s[cn * 32 + l4 * 8 + 4];
        bf16x8 pf = pexp8s(ka, kb, a, negM, zacc);

        // in-flight = chunks {cn, cn+1} (4 insts); keep cn+1's 2 in flight
        asm volatile("s_waitcnt vmcnt(2)" ::: "memory");
        __builtin_amdgcn_sched_barrier(0);
        __builtin_amdgcn_s_barrier();
        __builtin_amdgcn_sched_barrier(0);
        if (cn + 2 <= 7) DMA(cn + 2, (cn + 2) % 3);
        __builtin_amdgcn_sched_barrier(0);

        __builtin_amdgcn_s_setprio(1);
#pragma unroll
        for (int n = 0; n < 8; ++n) {
            bf16x8 uf = *(const bf16x8*)&u_l[cur][n * 512 + lane * 8];
            acc[n] = __builtin_amdgcn_mfma_f32_16x16x32_bf16(pf, uf, acc[n], 0, 0, 0);
        }
        __builtin_amdgcn_s_setprio(0);
    }
    {   // tail: chunk 7 (buf 7%3 == 1)
        float4 ka = *(const float4*)&ks_s[7 * 32 + l4 * 8];
        float4 kb = *(const float4*)&ks_s[7 * 32 + l4 * 8 + 4];
        bf16x8 pf = pexp8s(ka, kb, a, negM, zacc);
        asm volatile("s_waitcnt vmcnt(0)" ::: "memory");
        __builtin_amdgcn_sched_barrier(0);
        __builtin_amdgcn_s_barrier();
        __builtin_amdgcn_sched_barrier(0);
#pragma unroll
        for (int n = 0; n < 8; ++n) {
            bf16x8 uf = *(const bf16x8*)&u_l[1][n * 512 + lane * 8];
            acc[n] = __builtin_amdgcn_mfma_f32_16x16x32_bf16(pf, uf, acc[n], 0, 0, 0);
        }
    }
#undef DMA

    zacc += __shfl_xor(zacc, 16);
    zacc += __shfl_xor(zacc, 32);
    if (l4 == 0 && grow < NG)
        pz[(bh * 8 + sl) * NG + grow] = zacc;

    // C/D layout col=lane&15, row=(lane>>4)*4+reg; bf16 stores
#pragma unroll
    for (int r = 0; r < 4; ++r) {
        int g = gt * 64 + wid * 16 + l4 * 4 + r;
        if (g < NG) {
            unsigned short* row = pC + ((size_t)(bh * 8 + sl) * NG + g) * 128;
#pragma unroll
            for (int n = 0; n < 8; ++n)
                row[n * 16 + l15] = f2bf(acc[n][r]);
        }
    }
}

// ---- k_n: tablef[bh][g][kk] = (1/z) sum_m (sum_sl C)[g][m] * W2[h][kk][m] ----
// grid 128 x 256: (bh, gt). Reads bf16 partials, writes dense f32 table.
__global__ __launch_bounds__(256) void k_n(const unsigned short* __restrict__ pC,
                                           const float* __restrict__ pz,
                                           const float* __restrict__ W2,
                                           float* __restrict__ tf) {
    int L = blockIdx.x;
    int bh = L >> 2, gt = L & 3;
    int h = bh & 7;
    int tid = threadIdx.x;
    int lane = tid & 63, wid = tid >> 6;
    int wr = wid >> 1, wc = wid & 1;
    int l15 = lane & 15, l4 = lane >> 4;

    const float* w2h = W2 + h * 16384;

    f32x4 acc[2][4];
#pragma unroll
    for (int mg = 0; mg < 2; ++mg)
#pragma unroll
        for (int nt = 0; nt < 4; ++nt) acc[mg][nt] = (f32x4)0.f;

#pragma unroll
    for (int kq = 0; kq < 4; ++kq) {
        bf16x8 af[2], bfr[4];
#pragma unroll
        for (int mg = 0; mg < 2; ++mg) {
            int g = gt * 64 + wr * 32 + mg * 16 + l15;
            float sa[8] = {};
#pragma unroll
            for (int sl = 0; sl < 8; ++sl) {
                const unsigned short* p =
                    pC + ((size_t)(bh * 8 + sl) * NG + g) * 128 + kq * 32 + l4 * 8;
                uint4 v = *(const uint4*)p;
                sa[0] += __uint_as_float(v.x << 16);
                sa[1] += __uint_as_float(v.x & 0xFFFF0000u);
                sa[2] += __uint_as_float(v.y << 16);
                sa[3] += __uint_as_float(v.y & 0xFFFF0000u);
                sa[4] += __uint_as_float(v.z << 16);
                sa[5] += __uint_as_float(v.z & 0xFFFF0000u);
                sa[6] += __uint_as_float(v.w << 16);
                sa[7] += __uint_as_float(v.w & 0xFFFF0000u);
            }
            af[mg] = pack8(make_float4(sa[0], sa[1], sa[2], sa[3]),
                           make_float4(sa[4], sa[5], sa[6], sa[7]));
        }
#pragma unroll
        for (int nt = 0; nt < 4; ++nt) {
            int kk = wc * 64 + nt * 16 + l15;
            const float* src = w2h + kk * 128 + kq * 32 + l4 * 8;
            bfr[nt] = pack8(*(const float4*)src, *(const float4*)(src + 4));
        }
#pragma unroll
        for (int mg = 0; mg < 2; ++mg)
#pragma unroll
            for (int nt = 0; nt < 4; ++nt)
                acc[mg][nt] = __builtin_amdgcn_mfma_f32_16x16x32_bf16(
                    af[mg], bfr[nt], acc[mg][nt], 0, 0, 0);
    }

#pragma unroll
    for (int mg = 0; mg < 2; ++mg) {
#pragma unroll
        for (int r = 0; r < 4; ++r) {
            int g = gt * 64 + wr * 32 + mg * 16 + l4 * 4 + r;
            if (g < NG) {
                float z = 0.f;
#pragma unroll
                for (int sl = 0; sl < 8; ++sl) z += pz[(bh * 8 + sl) * NG + g];
                float zinv = 1.f / z;
                float* row = tf + ((size_t)bh * NG + g) * 128;
#pragma unroll
                for (int nt = 0; nt < 4; ++nt)
                    row[wc * 64 + nt * 16 + l15] = acc[mg][nt][r] * zinv;
            }
        }
    }
}

// ---- k_eval: y = bo + sum_h Lagrange4(tablef[bh], p(a_bh,t)) ----  grid 512
__global__ __launch_bounds__(256) void k_eval(const float* __restrict__ qs,
                                              const float* __restrict__ tablef,
                                              const unsigned* __restrict__ mmu,
                                              const float* __restrict__ bo,
                                              float* __restrict__ y) {
    int blk = blockIdx.x;
    int b = blk >> 7;
    int t = (blk & 127) * 16 + (threadIdx.x >> 4);
    int kk0 = (threadIdx.x & 15) * 8;

    float acc[8];
#pragma unroll
    for (int j = 0; j < 8; ++j) acc[j] = bo[kk0 + j];

#pragma unroll
    for (int h = 0; h < 8; ++h) {
        int bh = b * 8 + h;
        float a = qs[bh * 2048 + t] * A2SCALE;
        float amin = fdec(mmu[bh * 4]) * A2SCALE;
        float amax = fdec(mmu[bh * 4 + 1]) * A2SCALE;
        float hs = fmaxf(amax - amin, 1e-6f) * (1.f / (NG - 1));
        float p = (a - amin) / hs;
        int g1 = (int)p;
        g1 = g1 < 1 ? 1 : (g1 > NG - 3 ? NG - 3 : g1);
        float u = p - (float)g1;
        float um1 = u - 1.f, um2 = u - 2.f, up1 = u + 1.f;
        float w0 = -u * um1 * um2 * (1.f / 6.f);
        float w1 = up1 * um1 * um2 * 0.5f;
        float w2 = -up1 * u * um2 * 0.5f;
        float w3 = up1 * u * um1 * (1.f / 6.f);
        const float* base = tablef + ((size_t)bh * NG + (g1 - 1)) * 128 + kk0;
#pragma unroll
        for (int v = 0; v < 2; ++v) {
            float4 r0 = *(const float4*)(base + v * 4);
            float4 r1 = *(const float4*)(base + 128 + v * 4);
            float4 r2 = *(const float4*)(base + 256 + v * 4);
            float4 r3 = *(const float4*)(base + 384 + v * 4);
            acc[v * 4 + 0] += w0 * r0.x + w1 * r1.x + w2 * r2.x + w3 * r3.x;
            acc[v * 4 + 1] += w0 * r0.y + w1 * r1.y + w2 * r2.y + w3 * r3.y;
            acc[v * 4 + 2] += w0 * r0.z + w1 * r1.z + w2 * r2.z + w3 * r3.z;
            acc[v * 4 + 3] += w0 * r0.w + w1 * r1.w + w2 * r2.w + w3 * r3.w;
        }
    }
    float* yp = y + ((size_t)b * 2048 + t) * 128 + kk0;
    *(float4*)yp = make_float4(acc[0], acc[1], acc[2], acc[3]);
    *(float4*)(yp + 4) = make_float4(acc[4], acc[5], acc[6], acc[7]);
}

extern "C" void kernel_launch(void* const* d_in, const int* in_sizes, int n_in,
                              void* d_out, int out_size, void* d_ws, size_t ws_size,
                              hipStream_t stream) {
    const float* x  = (const float*)d_in[0];
    const float* Wq = (const float*)d_in[1];
    const float* Wk = (const float*)d_in[2];
    const float* Wv = (const float*)d_in[3];
    const float* Wo = (const float*)d_in[4];
    const float* bo = (const float*)d_in[5];
    float* y  = (float*)d_out;
    float* ws = (float*)d_ws;
    (void)in_sizes; (void)n_in; (void)out_size; (void)ws_size;

    unsigned short* xbf = (unsigned short*)(ws + OFF_XB);
    unsigned* mmu = (unsigned*)(ws + OFF_MMU);
    float* pz = ws + OFF_PZ;
    float* tf = ws + OFF_TF;
    unsigned short* pC = (unsigned short*)(ws + OFF_PC);

    k_prep1<<<576, 256, 0, stream>>>(Wq, Wk, Wv, Wo, ws, ws + OFF_W2, mmu);
    k_prep2<<<256, 256, 0, stream>>>(x, ws, ws + OFF_QS, ws + OFF_KS, xbf, mmu);
    k_c<<<1024, 256, 0, stream>>>(ws + OFF_KS, xbf, mmu, pC, pz);
    k_n<<<128, 256, 0, stream>>>(pC, pz, ws + OFF_W2, tf);
    k_eval<<<512, 256, 0, stream>>>(ws + OFF_QS, tf, mmu, bo, y);
}

// Round 17
// 71.955 us; speedup vs baseline: 1.0855x; 1.0855x over previous
//
#include <hip/hip_runtime.h>
#include <math.h>

// Problem constants
#define NB 4
#define NC 2048
#define NH 8
#define NK 128
#define NG 255          // a-grid points per (b,h)

// exp2-domain logit scale: log2(e)/sqrt(128)
#define A2SCALE (1.4426950408889634f * 0.08838834764831845f)

typedef __attribute__((ext_vector_type(8))) short bf16x8;
typedef __attribute__((ext_vector_type(4))) float f32x4;

// ---------------- ws layout (float offsets) ----------------
// wspart [4][2048]           @ 0        (8192)
// W2     [8][128][128]       @ 8192     (131072)
// qs     [32][2048]          @ 139264
// ks     [32][2048]          @ 204800
// u bf16 [32][64ig][8nt][64lane][8j] @ 270336 (8,388,608 ushort = 4,194,304 f)
// partsN [32][4sl][255][128] @ 4464640  (4,177,920) -> slice0 becomes tablef
// mmu    [32][4] uint        @ 8642560  (128 u32 = 128 f)
// end 8,642,688 < 8,652,864 (R0-proven footprint)
// parts_z [32][4][255] lives in d_out (overwritten by k_eval)
#define OFF_W2   8192
#define OFF_QS   139264
#define OFF_KS   204800
#define OFF_U    270336
#define OFF_PN   4464640
#define OFF_MMU  8642560

__device__ static inline float exp2_hw(float x) {
#if __has_builtin(__builtin_amdgcn_exp2f)
    return __builtin_amdgcn_exp2f(x);
#else
    float r;
    asm volatile("v_exp_f32 %0, %1\n\ts_nop 1" : "=v"(r) : "v"(x));
    return r;
#endif
}

__device__ static inline unsigned cvtpk(float lo, float hi) {
    unsigned r;
    asm("v_cvt_pk_bf16_f32 %0, %1, %2" : "=v"(r) : "v"(lo), "v"(hi));
    return r;
}

__device__ static inline bf16x8 pack8(float4 a, float4 b) {
    union { unsigned u[4]; bf16x8 v; } r;
    r.u[0] = cvtpk(a.x, a.y);
    r.u[1] = cvtpk(a.z, a.w);
    r.u[2] = cvtpk(b.x, b.y);
    r.u[3] = cvtpk(b.z, b.w);
    return r.v;
}

// order-preserving float <-> uint key (for atomicMin/Max)
__device__ static inline unsigned fenc(float f) {
    unsigned b = __float_as_uint(f);
    return (b & 0x80000000u) ? ~b : (b | 0x80000000u);
}
__device__ static inline float fdec(unsigned k) {
    return __uint_as_float((k & 0x80000000u) ? (k & 0x7FFFFFFFu) : ~k);
}

// 8 exps of (a*k + negM) packed to a bf16x8 A-fragment; accumulates sum in z
__device__ static inline bf16x8 pexp8s(float4 ka, float4 kb, float a, float negM,
                                       float& z) {
    float e0 = exp2_hw(fmaf(a, ka.x, negM));
    float e1 = exp2_hw(fmaf(a, ka.y, negM));
    float e2 = exp2_hw(fmaf(a, ka.z, negM));
    float e3 = exp2_hw(fmaf(a, ka.w, negM));
    float e4 = exp2_hw(fmaf(a, kb.x, negM));
    float e5 = exp2_hw(fmaf(a, kb.y, negM));
    float e6 = exp2_hw(fmaf(a, kb.z, negM));
    float e7 = exp2_hw(fmaf(a, kb.w, negM));
    z += ((e0 + e1) + (e2 + e3)) + ((e4 + e5) + (e6 + e7));
    union { unsigned u[4]; bf16x8 v; } r;
    r.u[0] = cvtpk(e0, e1);
    r.u[1] = cvtpk(e2, e3);
    r.u[2] = cvtpk(e4, e5);
    r.u[3] = cvtpk(e6, e7);
    return r.v;
}

// ---- prep1: (blk<64) wsum + mmu init ; (blk>=64) W2 ----  grid 576 x 256
// (R13 body + mmu init)
__global__ __launch_bounds__(256) void k_prep1(const float* __restrict__ Wq,
                                               const float* __restrict__ Wk,
                                               const float* __restrict__ Wv,
                                               const float* __restrict__ Wo,
                                               float* __restrict__ wspart,
                                               float* __restrict__ W2,
                                               unsigned* __restrict__ mmu) {
    int blk = blockIdx.x;
    int tid = threadIdx.x;
    __shared__ float sh[256];
    if (blk < 64) {
        int which = blk >> 5, h = (blk >> 2) & 7, eq = blk & 3;
        const float* W = which ? Wk : Wq;
        int m = tid & 127, part = tid >> 7;
        const float* base = W + (h * 128 + eq * 32 + part * 16) * 128 + m;
        float s = 0.f;
#pragma unroll
        for (int e = 0; e < 16; ++e) s += base[e * 128];
        if (part) sh[m] = s;
        __syncthreads();
        if (!part) wspart[eq * 2048 + which * 1024 + h * 128 + m] = s + sh[m];
        if (blk == 0 && tid < 128)
            mmu[tid] = (tid & 1) ? 0u : 0xFFFFFFFFu;   // min=MAXKEY, max=0
    } else {
        int idx = blk - 64;                    // 0..511
        int h = idx >> 6;
        int kl = tid >> 7;                     // 0..1
        int kk = (idx & 63) * 2 + kl;
        int m = tid & 127;
        float* wo_s = sh;                      // [2][128]
        wo_s[kl * 128 + m] = Wo[kk * 1024 + h * 128 + m];
        __syncthreads();
        const float* base = Wv + (h * 128) * 128 + m;
        const float* wrow = &wo_s[kl * 128];
        float s = 0.f;
#pragma unroll 4
        for (int e = 0; e < 128; ++e) s += base[e * 128] * wrow[e];
        W2[(h * 128 + kk) * 128 + m] = s;
    }
}

// ---- prep2: (blk<256) qs/ks + mmu atomics ; (blk>=256) u-GEMM ----
// grid 768 x 256 (R13 body + mmu atomics in qsks branch)
__global__ __launch_bounds__(256) void k_prep2(const float* __restrict__ x,
                                               const float* __restrict__ wspart,
                                               const float* __restrict__ W2,
                                               float* __restrict__ qs,
                                               float* __restrict__ ks,
                                               unsigned short* __restrict__ u16,
                                               unsigned* __restrict__ mmu) {
    __shared__ __align__(16) unsigned char smem_u8[32768];
    int tid = threadIdx.x;
    int blk = blockIdx.x;
    if (blk < 256) {
        float* xs = (float*)smem_u8;              // [32][129]
        float* wsum = (float*)smem_u8 + 32 * 129; // [2048]
        for (int j = tid; j < 2048; j += 256)
            wsum[j] = wspart[j] + wspart[2048 + j] + wspart[4096 + j] + wspart[6144 + j];
        int row0 = blk * 32;
        for (int j = tid; j < 32 * 128; j += 256) {
            int r = j >> 7, m = j & 127;
            xs[r * 129 + m] = x[(size_t)(row0 + r) * 128 + m];
        }
        __syncthreads();
#pragma unroll
        for (int jj = 0; jj < 2; ++jj) {
            int o = tid + 256 * jj;
            int r = o & 31;
            int q = o >> 5;
            int which = q >> 3, h = q & 7;
            const float* wrow = &wsum[which * 1024 + h * 128];
            const float* xrow = &xs[r * 129];
            float s = 0.f;
#pragma unroll 4
            for (int m = 0; m < 128; ++m) s += xrow[m] * wrow[m];
            int row = row0 + r, b = row >> 11, t = row & 2047;
            float* dst = which ? ks : qs;
            dst[(b * 8 + h) * 2048 + t] = s;
            // group (32 lanes = one (which,h)) min/max -> one atomic each
            float gmn = s, gmx = s;
#pragma unroll
            for (int off = 1; off <= 16; off <<= 1) {
                gmn = fminf(gmn, __shfl_xor(gmn, off));
                gmx = fmaxf(gmx, __shfl_xor(gmx, off));
            }
            if (r == 0) {
                unsigned* mb = &mmu[(b * 8 + h) * 4 + which * 2];
                atomicMin(&mb[0], fenc(gmn));
                atomicMax(&mb[1], fenc(gmx));
            }
        }
    } else {
        int gid = blk - 256;
        int xcd = gid & 7, s = gid >> 3;
        int bh = xcd * 4 + (s >> 4);
        int it = s & 15;
        int b = bh >> 3, h = bh & 7;
        int lane = tid & 63, wid = tid >> 6;
        int wr = wid >> 1, wc = wid & 1;
        int l15 = lane & 15, l4 = lane >> 4;

        const float* xb = x + (size_t)(b * 2048 + it * 128) * 128;
        const float* w2h = W2 + h * 16384;

        f32x4 acc[4][4];
#pragma unroll
        for (int m = 0; m < 4; ++m)
#pragma unroll
            for (int n = 0; n < 4; ++n) acc[m][n] = (f32x4)0.f;

#pragma unroll
        for (int mg = 0; mg < 4; ++mg) {
            bf16x8 af[4], bfr[4];
#pragma unroll
            for (int m = 0; m < 4; ++m) {
                const float* src = xb + (wr * 64 + m * 16 + l15) * 128 + mg * 32 + l4 * 8;
                af[m] = pack8(*(const float4*)src, *(const float4*)(src + 4));
            }
#pragma unroll
            for (int n = 0; n < 4; ++n) {
                const float* src = w2h + (wc * 64 + n * 16 + l15) * 128 + mg * 32 + l4 * 8;
                bfr[n] = pack8(*(const float4*)src, *(const float4*)(src + 4));
            }
#pragma unroll
            for (int m = 0; m < 4; ++m)
#pragma unroll
                for (int n = 0; n < 4; ++n)
                    acc[m][n] = __builtin_amdgcn_mfma_f32_16x16x32_bf16(
                        af[m], bfr[n], acc[m][n], 0, 0, 0);
        }

        // transpose acc -> u B-frag layout through LDS (32 KB)
        unsigned* u_sh = (unsigned*)smem_u8;
#pragma unroll
        for (int m = 0; m < 4; ++m) {
            int i_base = wr * 64 + m * 16 + l4 * 4;
            int ig = i_base >> 5;
            int lg = 16 * ((i_base >> 3) & 3);
            int jp = (i_base & 7) >> 1;          // 0 or 2
#pragma unroll
            for (int n = 0; n < 4; ++n) {
                int kk = wc * 64 + n * 16 + l15;
                int lp = (kk & 15) + lg;
                int idx = ((ig * 8 + (kk >> 4)) * 64 + lp) * 4 + jp;
                uint2 w;
                w.x = cvtpk(acc[m][n][0], acc[m][n][1]);
                w.y = cvtpk(acc[m][n][2], acc[m][n][3]);
                *(uint2*)&u_sh[idx] = w;
            }
        }
        __syncthreads();
        unsigned short* ub = u16 + ((size_t)(b * 8 + h) * 64 + it * 4) * 4096;
#pragma unroll
        for (int q = 0; q < 8; ++q)
            ((uint4*)ub)[tid + q * 256] = ((const uint4*)u_sh)[tid + q * 256];
    }
}

// ---- k_table: tabulate N_g, z_g on the a-grid, per (bh, 64-g tile, i-slice) ----
// grid 512 x 256 (R13 convoy verbatim; prologue = mmu decode + 512-float ks slice)
__global__ __launch_bounds__(256, 2) void k_table(const float* __restrict__ ks,
                                                  const unsigned short* __restrict__ ub,
                                                  const unsigned* __restrict__ mmu,
                                                  float* __restrict__ pN,
                                                  float* __restrict__ pz) {
    int L = blockIdx.x;
    int xcd = L & 7, s = L >> 3;
    int bh = xcd * 4 + (s >> 4);
    int rem = s & 15;
    int gt = rem >> 2, sl = rem & 3;
    int tid = threadIdx.x;
    int lane = tid & 63, wid = tid >> 6;
    int l15 = lane & 15, l4 = lane >> 4;

    __shared__ float ks_s[512];
    __shared__ __align__(16) unsigned short u_l[3][4096];

    // decode range keys (formulas textually identical to k_eval)
    float amin = fdec(mmu[bh * 4]) * A2SCALE;
    float amax = fdec(mmu[bh * 4 + 1]) * A2SCALE;
    float hstep = fmaxf(amax - amin, 1e-6f) * (1.f / (NG - 1));
    float kmn = fdec(mmu[bh * 4 + 2]);
    float kmx = fdec(mmu[bh * 4 + 3]);

    // stage this slice's ks (512 floats)
    if (tid < 128)
        ((float4*)ks_s)[tid] = ((const float4*)(ks + bh * 2048 + sl * 512))[tid];

    int grow = gt * 64 + wid * 16 + l15;
    float a = fmaf((float)grow, hstep, amin);
    float negM = -(a > 0.f ? a * kmx : a * kmn);   // exact max over ALL i
    float zacc = 0.f;

    const unsigned short* gub = ub + (size_t)bh * 262144 + (size_t)sl * 65536;

    f32x4 acc[8];
#pragma unroll
    for (int n = 0; n < 8; ++n) acc[n] = (f32x4)0.f;

    __syncthreads();   // ks_s ready; all prologue VMEM drained (count invariant)

#define DMA(cnv, buf) do {                                                     \
    const unsigned short* src_ = gub + (size_t)(cnv) * 4096;                   \
    _Pragma("unroll")                                                          \
    for (int q_ = 0; q_ < 2; ++q_) {                                           \
        int seg_ = q_ * 4 + wid;                                               \
        __builtin_amdgcn_global_load_lds(                                      \
            (const __attribute__((address_space(1))) unsigned int*)(src_ + seg_ * 512 + lane * 8), \
            (__attribute__((address_space(3))) unsigned int*)(&u_l[buf][seg_ * 512]),              \
            16, 0, 0);                                                         \
    }                                                                          \
} while (0)

    DMA(0, 0);
    DMA(1, 1);
    for (int cn = 0; cn < 15; ++cn) {
        int cur = cn % 3;
        float4 ka = *(const float4*)&ks_s[cn * 32 + l4 * 8];
        float4 kb = *(const float4*)&ks_s[cn * 32 + l4 * 8 + 4];
        bf16x8 pf = pexp8s(ka, kb, a, negM, zacc);

        asm volatile("s_waitcnt vmcnt(2)" ::: "memory");
        __builtin_amdgcn_sched_barrier(0);
        __builtin_amdgcn_s_barrier();
        __builtin_amdgcn_sched_barrier(0);
        if (cn + 2 <= 15) DMA(cn + 2, (cn + 2) % 3);
        __builtin_amdgcn_sched_barrier(0);

        __builtin_amdgcn_s_setprio(1);
#pragma unroll
        for (int n = 0; n < 8; ++n) {
            bf16x8 uf = *(const bf16x8*)&u_l[cur][n * 512 + lane * 8];
            acc[n] = __builtin_amdgcn_mfma_f32_16x16x32_bf16(pf, uf, acc[n], 0, 0, 0);
        }
        __builtin_amdgcn_s_setprio(0);
    }
    {   // tail: chunk 15 (buf 15%3 == 0)
        float4 ka = *(const float4*)&ks_s[15 * 32 + l4 * 8];
        float4 kb = *(const float4*)&ks_s[15 * 32 + l4 * 8 + 4];
        bf16x8 pf = pexp8s(ka, kb, a, negM, zacc);
        asm volatile("s_waitcnt vmcnt(0)" ::: "memory");
        __builtin_amdgcn_sched_barrier(0);
        __builtin_amdgcn_s_barrier();
        __builtin_amdgcn_sched_barrier(0);
#pragma unroll
        for (int n = 0; n < 8; ++n) {
            bf16x8 uf = *(const bf16x8*)&u_l[0][n * 512 + lane * 8];
            acc[n] = __builtin_amdgcn_mfma_f32_16x16x32_bf16(pf, uf, acc[n], 0, 0, 0);
        }
    }
#undef DMA

    zacc += __shfl_xor(zacc, 16);
    zacc += __shfl_xor(zacc, 32);
    if (l4 == 0 && grow < NG)
        pz[(bh * 4 + sl) * NG + grow] = zacc;

    // C/D layout col=lane&15, row=(lane>>4)*4+reg. Plain stores (exclusive).
#pragma unroll
    for (int r = 0; r < 4; ++r) {
        int g = gt * 64 + wid * 16 + l4 * 4 + r;
        if (g < NG) {
            float* row = pN + ((size_t)(bh * 4 + sl) * NG + g) * 128;
#pragma unroll
            for (int n = 0; n < 8; ++n)
                row[n * 16 + l15] = acc[n][r];
        }
    }
}

// ---- k_reduce: tablef[bh][g][kk] = sum_sl N / sum_sl z (in-place slice 0) ----
// grid 256 x 256 (R13-identical)
__global__ __launch_bounds__(256) void k_reduce(float* __restrict__ pN,
                                                const float* __restrict__ pz) {
    int blk = blockIdx.x;
    int bh = blk >> 3;
    int g = (blk & 7) * 32 + (threadIdx.x >> 3);
    if (g >= NG) return;
    int kq = (threadIdx.x & 7) * 16;   // 16 kk per thread
    float z = pz[(bh * 4 + 0) * NG + g] + pz[(bh * 4 + 1) * NG + g] +
              pz[(bh * 4 + 2) * NG + g] + pz[(bh * 4 + 3) * NG + g];
    float zinv = 1.f / z;
    size_t r0 = ((size_t)(bh * 4 + 0) * NG + g) * 128 + kq;
    size_t r1 = ((size_t)(bh * 4 + 1) * NG + g) * 128 + kq;
    size_t r2 = ((size_t)(bh * 4 + 2) * NG + g) * 128 + kq;
    size_t r3 = ((size_t)(bh * 4 + 3) * NG + g) * 128 + kq;
#pragma unroll
    for (int v = 0; v < 4; ++v) {
        float4 s0 = *(const float4*)&pN[r0 + v * 4];
        float4 s1 = *(const float4*)&pN[r1 + v * 4];
        float4 s2 = *(const float4*)&pN[r2 + v * 4];
        float4 s3 = *(const float4*)&pN[r3 + v * 4];
        float4 o;
        o.x = (s0.x + s1.x + s2.x + s3.x) * zinv;
        o.y = (s0.y + s1.y + s2.y + s3.y) * zinv;
        o.z = (s0.z + s1.z + s2.z + s3.z) * zinv;
        o.w = (s0.w + s1.w + s2.w + s3.w) * zinv;
        *(float4*)&pN[r0 + v * 4] = o;   // tablef overlays slice 0
    }
}

// ---- k_eval: y = bo + sum_h Lagrange4(tablef[bh], p(a_bh,t)) ----  grid 512
// (R13 body; mmu decode instead of mm)
__global__ __launch_bounds__(256) void k_eval(const float* __restrict__ qs,
                                              const float* __restrict__ tablef,
                                              const unsigned* __restrict__ mmu,
                                              const float* __restrict__ bo,
                                              float* __restrict__ y) {
    int blk = blockIdx.x;
    int b = blk >> 7;
    int t = (blk & 127) * 16 + (threadIdx.x >> 4);
    int kk0 = (threadIdx.x & 15) * 8;

    float acc[8];
#pragma unroll
    for (int j = 0; j < 8; ++j) acc[j] = bo[kk0 + j];

#pragma unroll
    for (int h = 0; h < 8; ++h) {
        int bh = b * 8 + h;
        float a = qs[bh * 2048 + t] * A2SCALE;
        float amin = fdec(mmu[bh * 4]) * A2SCALE;
        float amax = fdec(mmu[bh * 4 + 1]) * A2SCALE;
        float hs = fmaxf(amax - amin, 1e-6f) * (1.f / (NG - 1));
        float p = (a - amin) / hs;
        int g1 = (int)p;
        g1 = g1 < 1 ? 1 : (g1 > NG - 3 ? NG - 3 : g1);
        float u = p - (float)g1;
        float um1 = u - 1.f, um2 = u - 2.f, up1 = u + 1.f;
        float w0 = -u * um1 * um2 * (1.f / 6.f);
        float w1 = up1 * um1 * um2 * 0.5f;
        float w2 = -up1 * u * um2 * 0.5f;
        float w3 = up1 * u * um1 * (1.f / 6.f);
        const float* base = tablef + ((size_t)(bh * 4) * NG + (g1 - 1)) * 128 + kk0;
#pragma unroll
        for (int v = 0; v < 2; ++v) {
            float4 r0 = *(const float4*)(base + v * 4);
            float4 r1 = *(const float4*)(base + 128 + v * 4);
            float4 r2 = *(const float4*)(base + 256 + v * 4);
            float4 r3 = *(const float4*)(base + 384 + v * 4);
            acc[v * 4 + 0] += w0 * r0.x + w1 * r1.x + w2 * r2.x + w3 * r3.x;
            acc[v * 4 + 1] += w0 * r0.y + w1 * r1.y + w2 * r2.y + w3 * r3.y;
            acc[v * 4 + 2] += w0 * r0.z + w1 * r1.z + w2 * r2.z + w3 * r3.z;
            acc[v * 4 + 3] += w0 * r0.w + w1 * r1.w + w2 * r2.w + w3 * r3.w;
        }
    }
    float* yp = y + ((size_t)b * 2048 + t) * 128 + kk0;
    *(float4*)yp = make_float4(acc[0], acc[1], acc[2], acc[3]);
    *(float4*)(yp + 4) = make_float4(acc[4], acc[5], acc[6], acc[7]);
}

extern "C" void kernel_launch(void* const* d_in, const int* in_sizes, int n_in,
                              void* d_out, int out_size, void* d_ws, size_t ws_size,
                              hipStream_t stream) {
    const float* x  = (const float*)d_in[0];
    const float* Wq = (const float*)d_in[1];
    const float* Wk = (const float*)d_in[2];
    const float* Wv = (const float*)d_in[3];
    const float* Wo = (const float*)d_in[4];
    const float* bo = (const float*)d_in[5];
    float* y  = (float*)d_out;
    float* ws = (float*)d_ws;
    (void)in_sizes; (void)n_in; (void)out_size; (void)ws_size;

    unsigned short* u16 = (unsigned short*)(ws + OFF_U);
    unsigned* mmu = (unsigned*)(ws + OFF_MMU);
    float* pN = ws + OFF_PN;
    float* pz = y;             // scratch in d_out; overwritten by k_eval

    k_prep1<<<576, 256, 0, stream>>>(Wq, Wk, Wv, Wo, ws, ws + OFF_W2, mmu);
    k_prep2<<<768, 256, 0, stream>>>(x, ws, ws + OFF_W2, ws + OFF_QS, ws + OFF_KS,
                                     u16, mmu);
    k_table<<<512, 256, 0, stream>>>(ws + OFF_KS, u16, mmu, pN, pz);
    k_reduce<<<256, 256, 0, stream>>>(pN, pz);
    k_eval<<<512, 256, 0, stream>>>(ws + OFF_QS, pN, mmu, bo, y);
}